// Round 17
// baseline (116.286 us; speedup 1.0000x reference)
//
#include <hip/hip_runtime.h>
#include <stdint.h>

#define NCH 128            // C_IN == C_OUT == 128
#define BK_SHIFT 7         // 128 targets per bucket
#define BK_TGTS 128
#define NBUCK_MAX 512      // 391 used
#define BKT_CAP 5120       // fixed per-bucket capacity (mean 4092, +16 sigma)
#define PT_EDGES 2048      // edges per partition tile (782 blocks -> TLP)

typedef short bf16x8 __attribute__((ext_vector_type(8)));
typedef float f32x4 __attribute__((ext_vector_type(4)));
typedef float f32x2 __attribute__((ext_vector_type(2)));

// ---------------------------------------------------------------------------
// bf16 helpers (manual RNE pack; decode via bit shift)
// ---------------------------------------------------------------------------
__device__ __forceinline__ unsigned short f2bf(float f) {
    union { float f; uint32_t u; } v; v.f = f;
    uint32_t u = v.u;
    uint32_t r = u + 0x7fffu + ((u >> 16) & 1u);
    return (unsigned short)(r >> 16);
}
__device__ __forceinline__ float bf2f(unsigned short h) {
    return __uint_as_float((uint32_t)h << 16);
}
__device__ __forceinline__ float bflo(uint32_t u) { return __uint_as_float(u << 16); }
__device__ __forceinline__ float bfhi(uint32_t u) { return __uint_as_float(u & 0xffff0000u); }
// decode one u32 (2 bf16) into a packed float pair -> enables v_pk_add_f32
__device__ __forceinline__ f32x2 bfpair(uint32_t u) {
    f32x2 r;
    r.x = __uint_as_float(u << 16);
    r.y = __uint_as_float(u & 0xffff0000u);
    return r;
}

// ---------------------------------------------------------------------------
// prep_w: W (f32 128x128) -> fragment-swizzled bf16 hi/lo table (64 KB).
// Block 0 also zeroes the bucket cursors (replaces a memset dispatch).
// ---------------------------------------------------------------------------
__global__ __launch_bounds__(256) void prep_w_kernel(const float* __restrict__ W,
                                                     short* __restrict__ whl,
                                                     int* __restrict__ bcur) {
    if (blockIdx.x == 0) {
        for (int i = threadIdx.x; i < NBUCK_MAX; i += 256) bcur[i] = 0;
    }
    const int idx = blockIdx.x * 256 + threadIdx.x;   // 2048 = 16 ko x 128 n
    if (idx >= 2048) return;
    const int ko = idx >> 7;
    const int n = idx & 127;
    const int kt = ko >> 2, g = ko & 3;
    const int ct = n >> 4, l16 = n & 15;
    const int row = g * 16 + l16;
    bf16x8 vh, vl;
    #pragma unroll
    for (int e = 0; e < 8; ++e) {
        const float w = W[(size_t)(ko * 8 + e) * NCH + n];
        const unsigned short wh = f2bf(w);
        vh[e] = (short)wh;
        vl[e] = (short)f2bf(w - bf2f(wh));
    }
    *reinterpret_cast<bf16x8*>(&whl[(((0 * 4 + kt) * 8 + ct) * 64 + row) * 8]) = vh;
    *reinterpret_cast<bf16x8*>(&whl[(((1 * 4 + kt) * 8 + ct) * 64 + row) * 8]) = vl;
}

// ---------------------------------------------------------------------------
// Stage 1 (fused detect+count+partition): scatter edges into fixed-capacity
// bucket windows. Packed entry = {c:16 | r:16}; edges staged in REGISTERS
// (pk/rank), LDS only for the 391-bucket histogram -> high occupancy.
// NORMAL stores on the scatter (nt-store here = 8x write amp, R15).
// ---------------------------------------------------------------------------
__global__ __launch_bounds__(256) void partition_kernel(const int* __restrict__ ei, int E,
                                                        int nbuck,
                                                        int* __restrict__ bcur,
                                                        uint32_t* __restrict__ bkt) {
    __shared__ int hist[NBUCK_MAX];
    __shared__ int cbase[NBUCK_MAX];
    __shared__ int s_is64;
    const int t = threadIdx.x;
    const int e0 = blockIdx.x * PT_EDGES;
    const int cnt = min(PT_EDGES, E - e0);

    if (t == 0) s_is64 = 0;
    for (int i = t; i < NBUCK_MAX; i += 256) hist[i] = 0;
    __syncthreads();
    // int64 layout iff high words all zero (values < 50000; random int32 cols
    // can't all be 0 for 128 samples)
    if (t < 128 && ei[2 * t + 1] != 0) s_is64 = 1;
    __syncthreads();
    const bool is64 = (s_is64 == 0);

    uint32_t pk[PT_EDGES / 256];
    int rank[PT_EDGES / 256];
    #pragma unroll
    for (int j = 0; j < PT_EDGES / 256; ++j) {
        const int i = t + j * 256;
        pk[j] = 0u;
        rank[j] = 0;
        if (i < cnt) {
            int r, c;
            if (is64) {
                r = reinterpret_cast<const int2*>(ei)[(size_t)(e0 + i)].x;
                c = reinterpret_cast<const int2*>(ei)[(size_t)E + e0 + i].x;
            } else {
                r = ei[e0 + i];
                c = ei[(size_t)E + e0 + i];
            }
            pk[j] = ((uint32_t)c << 16) | (uint32_t)r;
            rank[j] = atomicAdd(&hist[c >> BK_SHIFT], 1);
        }
    }
    __syncthreads();
    for (int b = t; b < nbuck; b += 256) {
        cbase[b] = hist[b] ? atomicAdd(&bcur[b], hist[b]) : 0;
    }
    __syncthreads();
    #pragma unroll
    for (int j = 0; j < PT_EDGES / 256; ++j) {
        const int i = t + j * 256;
        if (i < cnt) {
            const int b = (int)(pk[j] >> (16 + BK_SHIFT));
            const int pos = cbase[b] + rank[j];
            if (pos < BKT_CAP) bkt[(size_t)b * BKT_CAP + pos] = pk[j];
        }
    }
}

// ---------------------------------------------------------------------------
// Stage 2: one block per bucket (self-computes its CSR base from bcur).
// Counting sort -> CSR offsets, dinv, u16 src entries. NO LDS staging:
// the bucket window is re-read from L2 in the scatter pass (8 MB re-read
// at L2 BW ~ free; LDS shrinks to ~1.3 KB -> thread-bound occupancy).
// ---------------------------------------------------------------------------
__global__ __launch_bounds__(256) void bucket_sort_kernel(const uint32_t* __restrict__ bkt,
                                                          const int* __restrict__ bcur,
                                                          int N, int nbuck,
                                                          unsigned short* __restrict__ entries,
                                                          int* __restrict__ offsets,
                                                          float* __restrict__ dinv) {
    __shared__ int hist[BK_TGTS];
    __shared__ int lofs[BK_TGTS];
    __shared__ int s_beg;
    const int b = blockIdx.x;
    const int t = threadIdx.x;
    const int c0 = b << BK_SHIFT;
    const int ntgt = min(BK_TGTS, N - c0);

    for (int i = t; i < BK_TGTS; i += 256) hist[i] = 0;
    if (t < 64) {
        int sum = 0;
        for (int i = t; i < b; i += 64) sum += min(bcur[i], BKT_CAP);
        #pragma unroll
        for (int d = 1; d < 64; d <<= 1) sum += __shfl_xor(sum, d);
        if (t == 0) s_beg = sum;
    }
    __syncthreads();
    const int beg = s_beg;
    const int nE = min(bcur[b], BKT_CAP);
    const int nE4 = nE & ~3;
    const uint32_t* win = bkt + (size_t)b * BKT_CAP;

    // pass A: histogram (uint4 reads)
    for (int i = t * 4; i < nE4; i += 1024) {
        const uint4 p = *reinterpret_cast<const uint4*>(win + i);
        atomicAdd(&hist[(int)(p.x >> 16) - c0], 1);
        atomicAdd(&hist[(int)(p.y >> 16) - c0], 1);
        atomicAdd(&hist[(int)(p.z >> 16) - c0], 1);
        atomicAdd(&hist[(int)(p.w >> 16) - c0], 1);
    }
    for (int i = nE4 + t; i < nE; i += 256) {
        atomicAdd(&hist[(int)(win[i] >> 16) - c0], 1);
    }
    __syncthreads();

    // exclusive scan of hist[0..127] in wave 0: lane owns {2t, 2t+1}
    if (t < 64) {
        const int h0 = hist[2 * t], h1 = hist[2 * t + 1];
        int s = h0 + h1;
        #pragma unroll
        for (int d = 1; d < 64; d <<= 1) {
            const int u = __shfl_up(s, d);
            if (t >= d) s += u;
        }
        const int ex = s - (h0 + h1);
        lofs[2 * t] = ex;
        lofs[2 * t + 1] = ex + h0;
    }
    __syncthreads();

    for (int i = t; i < ntgt; i += 256) {
        offsets[c0 + i] = beg + lofs[i];
        dinv[c0 + i] = rsqrtf((float)(hist[i] + 1));
    }
    if (t == 0 && b == nbuck - 1) offsets[N] = beg + nE;
    __syncthreads();

    // reuse hist as scatter cursors
    for (int i = t; i < BK_TGTS; i += 256) hist[i] = lofs[i];
    __syncthreads();

    // pass B: re-read window (L2-hot) and scatter u16 entries
    for (int i = t * 4; i < nE4; i += 1024) {
        const uint4 p = *reinterpret_cast<const uint4*>(win + i);
        int pos;
        pos = atomicAdd(&hist[(int)(p.x >> 16) - c0], 1); entries[beg + pos] = (unsigned short)(p.x & 0xffffu);
        pos = atomicAdd(&hist[(int)(p.y >> 16) - c0], 1); entries[beg + pos] = (unsigned short)(p.y & 0xffffu);
        pos = atomicAdd(&hist[(int)(p.z >> 16) - c0], 1); entries[beg + pos] = (unsigned short)(p.z & 0xffffu);
        pos = atomicAdd(&hist[(int)(p.w >> 16) - c0], 1); entries[beg + pos] = (unsigned short)(p.w & 0xffffu);
    }
    for (int i = nE4 + t; i < nE; i += 256) {
        const uint32_t p = win[i];
        const int pos = atomicAdd(&hist[(int)(p >> 16) - c0], 1);
        entries[beg + pos] = (unsigned short)(p & 0xffffu);
    }
}

// ---------------------------------------------------------------------------
// h = x @ W via MFMA bf16, 3-term split (from precomputed Wh/Wl table);
// output pre-scaled by dinv[row], flat layout hb[row][64 u32].
// 128 rows/block (two 64-row groups share the staged W and each bh/bl read).
// ---------------------------------------------------------------------------
__global__ __launch_bounds__(256) void gemm_xw_mfma_kernel(const float* __restrict__ x,
                                                           const short* __restrict__ whl,
                                                           const float* __restrict__ dinv,
                                                           uint32_t* __restrict__ hb, int N) {
    __shared__ short sW[2][4][8][64][8];
    const int t = threadIdx.x;

    // pure copy stage: 64 KB from the precomputed table
    {
        short* d = &sW[0][0][0][0][0];
        #pragma unroll
        for (int i = t * 8; i < 2 * 4 * 8 * 64 * 8; i += 256 * 8)
            *reinterpret_cast<bf16x8*>(d + i) = *reinterpret_cast<const bf16x8*>(whl + i);
    }
    __syncthreads();

    const int wave = t >> 6;
    const int lane = t & 63;
    const int g = lane >> 4;
    const int l16 = lane & 15;
    const int row0 = blockIdx.x * 128 + wave * 16;   // group 0; group 1 = +64
    if (row0 >= N) return;

    bf16x8 ah[2][4], al[2][4];
    float dn[2][4];
    #pragma unroll
    for (int grp = 0; grp < 2; ++grp) {
        const int rbase = row0 + grp * 64;
        const int arow = min(rbase + l16, N - 1);
        const float* xr = x + (size_t)arow * NCH + g * 8;
        #pragma unroll
        for (int kt = 0; kt < 4; ++kt) {
            const float4 v0 = *reinterpret_cast<const float4*>(xr + kt * 32);
            const float4 v1 = *reinterpret_cast<const float4*>(xr + kt * 32 + 4);
            const float vv[8] = {v0.x, v0.y, v0.z, v0.w, v1.x, v1.y, v1.z, v1.w};
            #pragma unroll
            for (int e = 0; e < 8; ++e) {
                const unsigned short h16 = f2bf(vv[e]);
                ah[grp][kt][e] = (short)h16;
                al[grp][kt][e] = (short)f2bf(vv[e] - bf2f(h16));
            }
        }
        #pragma unroll
        for (int r = 0; r < 4; ++r) dn[grp][r] = dinv[min(rbase + g * 4 + r, N - 1)];
    }

    #pragma unroll
    for (int ct = 0; ct < 8; ++ct) {
        f32x4 accA = {0.f, 0.f, 0.f, 0.f};
        f32x4 accB = {0.f, 0.f, 0.f, 0.f};
        #pragma unroll
        for (int kt = 0; kt < 4; ++kt) {
            const bf16x8 bh = *reinterpret_cast<const bf16x8*>(&sW[0][kt][ct][lane][0]);
            const bf16x8 bl = *reinterpret_cast<const bf16x8*>(&sW[1][kt][ct][lane][0]);
            accA = __builtin_amdgcn_mfma_f32_16x16x32_bf16(ah[0][kt], bh, accA, 0, 0, 0);
            accA = __builtin_amdgcn_mfma_f32_16x16x32_bf16(al[0][kt], bh, accA, 0, 0, 0);
            accA = __builtin_amdgcn_mfma_f32_16x16x32_bf16(ah[0][kt], bl, accA, 0, 0, 0);
            accB = __builtin_amdgcn_mfma_f32_16x16x32_bf16(ah[1][kt], bh, accB, 0, 0, 0);
            accB = __builtin_amdgcn_mfma_f32_16x16x32_bf16(al[1][kt], bh, accB, 0, 0, 0);
            accB = __builtin_amdgcn_mfma_f32_16x16x32_bf16(ah[1][kt], bl, accB, 0, 0, 0);
        }
        // C/D: col = ct*16 + (lane&15), row = rbase + (lane>>4)*4 + r
        #pragma unroll
        for (int grp = 0; grp < 2; ++grp) {
            const f32x4 acc = grp ? accB : accA;
            #pragma unroll
            for (int r = 0; r < 4; ++r) {
                const float v = acc[r] * dn[grp][r];
                const float o = __shfl_xor(v, 1);
                const int wrow = row0 + grp * 64 + g * 4 + r;
                if ((lane & 1) == 0 && wrow < N) {
                    const uint32_t p = (uint32_t)f2bf(v) | ((uint32_t)f2bf(o) << 16);
                    hb[(size_t)wrow * (NCH / 2) + ct * 8 + (l16 >> 1)] = p;
                }
            }
        }
    }
}

// ---------------------------------------------------------------------------
// SpMM: one wave per target node. 32 lanes x 8 B cover the 256 B bf16 row.
// Halves process even/odd local edges; first 64 entries preloaded into regs
// and broadcast via __shfl. 8-deep unroll -> 8 gathers in flight per half.
// Packed-pair (v_pk_add_f32) accumulate; non-temporal out store (full-line
// streaming only -- nt is NOT safe for scatters, see R15).
// ---------------------------------------------------------------------------
__global__ __launch_bounds__(256) void spmm_csr_kernel(const uint32_t* __restrict__ hb,
                                                       const unsigned short* __restrict__ entries,
                                                       const int* __restrict__ offsets,
                                                       const float* __restrict__ dinv,
                                                       const float* __restrict__ bias,
                                                       float* __restrict__ out, int N) {
    const int lane = threadIdx.x & 63;
    const int n = blockIdx.x * 4 + (threadIdx.x >> 6);
    if (n >= N) return;

    const int half = lane >> 5;
    const int sl = lane & 31;          // covers cols sl*4 .. sl*4+3

    const int beg = offsets[n];
    const int end = offsets[n + 1];
    const int len = end - beg;
    const int cnt0 = min(len, 64);

    int pre = 0;
    if (beg + lane < end) pre = (int)__builtin_nontemporal_load(entries + beg + lane);

    const uint32_t* __restrict__ hbs = hb + sl * 2;
    f32x2 acc01 = {0.f, 0.f};
    f32x2 acc23 = {0.f, 0.f};

    int j = 0;
    // 8-deep: all elements valid for BOTH halves iff 2j+16 <= cnt0
    for (; 2 * j + 16 <= cnt0; j += 8) {
        const int i0 = 2 * j + half;
        const int s0 = __shfl(pre, i0);
        const int s1 = __shfl(pre, i0 + 2);
        const int s2 = __shfl(pre, i0 + 4);
        const int s3 = __shfl(pre, i0 + 6);
        const int s4 = __shfl(pre, i0 + 8);
        const int s5 = __shfl(pre, i0 + 10);
        const int s6 = __shfl(pre, i0 + 12);
        const int s7 = __shfl(pre, i0 + 14);
        const uint2 u0 = *reinterpret_cast<const uint2*>(hbs + (size_t)s0 * (NCH / 2));
        const uint2 u1 = *reinterpret_cast<const uint2*>(hbs + (size_t)s1 * (NCH / 2));
        const uint2 u2 = *reinterpret_cast<const uint2*>(hbs + (size_t)s2 * (NCH / 2));
        const uint2 u3 = *reinterpret_cast<const uint2*>(hbs + (size_t)s3 * (NCH / 2));
        const uint2 u4 = *reinterpret_cast<const uint2*>(hbs + (size_t)s4 * (NCH / 2));
        const uint2 u5 = *reinterpret_cast<const uint2*>(hbs + (size_t)s5 * (NCH / 2));
        const uint2 u6 = *reinterpret_cast<const uint2*>(hbs + (size_t)s6 * (NCH / 2));
        const uint2 u7 = *reinterpret_cast<const uint2*>(hbs + (size_t)s7 * (NCH / 2));
        acc01 += bfpair(u0.x); acc23 += bfpair(u0.y);
        acc01 += bfpair(u1.x); acc23 += bfpair(u1.y);
        acc01 += bfpair(u2.x); acc23 += bfpair(u2.y);
        acc01 += bfpair(u3.x); acc23 += bfpair(u3.y);
        acc01 += bfpair(u4.x); acc23 += bfpair(u4.y);
        acc01 += bfpair(u5.x); acc23 += bfpair(u5.y);
        acc01 += bfpair(u6.x); acc23 += bfpair(u6.y);
        acc01 += bfpair(u7.x); acc23 += bfpair(u7.y);
    }
    for (; 2 * j + 8 <= cnt0; j += 4) {
        const int i0 = 2 * j + half;
        const int s0 = __shfl(pre, i0);
        const int s1 = __shfl(pre, i0 + 2);
        const int s2 = __shfl(pre, i0 + 4);
        const int s3 = __shfl(pre, i0 + 6);
        const uint2 u0 = *reinterpret_cast<const uint2*>(hbs + (size_t)s0 * (NCH / 2));
        const uint2 u1 = *reinterpret_cast<const uint2*>(hbs + (size_t)s1 * (NCH / 2));
        const uint2 u2 = *reinterpret_cast<const uint2*>(hbs + (size_t)s2 * (NCH / 2));
        const uint2 u3 = *reinterpret_cast<const uint2*>(hbs + (size_t)s3 * (NCH / 2));
        acc01 += bfpair(u0.x); acc23 += bfpair(u0.y);
        acc01 += bfpair(u1.x); acc23 += bfpair(u1.y);
        acc01 += bfpair(u2.x); acc23 += bfpair(u2.y);
        acc01 += bfpair(u3.x); acc23 += bfpair(u3.y);
    }
    // remainder: uniform count over halves; invalid element zeroed
    for (; 2 * j < cnt0; ++j) {
        const int i0 = 2 * j + half;
        const int s0 = __shfl(pre, min(i0, 63));
        uint2 u0 = *reinterpret_cast<const uint2*>(hbs + (size_t)s0 * (NCH / 2));
        if (i0 >= cnt0) { u0.x = 0u; u0.y = 0u; }
        acc01 += bfpair(u0.x); acc23 += bfpair(u0.y);
    }
    // rare tail (deg > 64): direct loads, no shfl
    for (int jj = beg + 64 + half; jj < end; jj += 2) {
        const int s0 = __builtin_nontemporal_load(entries + jj);
        const uint2 u0 = *reinterpret_cast<const uint2*>(hbs + (size_t)s0 * (NCH / 2));
        acc01 += bfpair(u0.x); acc23 += bfpair(u0.y);
    }

    float a0 = acc01.x, a1 = acc01.y, a2 = acc23.x, a3 = acc23.y;
    a0 += __shfl_xor(a0, 32);
    a1 += __shfl_xor(a1, 32);
    a2 += __shfl_xor(a2, 32);
    a3 += __shfl_xor(a3, 32);

    // self-loop: hb row n is dinv[n]*h[n]
    const uint2 us = *reinterpret_cast<const uint2*>(hbs + (size_t)n * (NCH / 2));
    a0 += bflo(us.x); a1 += bfhi(us.x); a2 += bflo(us.y); a3 += bfhi(us.y);

    const float s = dinv[n];
    if (half == 0) {
        const float4 bb = reinterpret_cast<const float4*>(bias)[sl];
        f32x4 o;
        o.x = fmaxf(a0 * s + bb.x, 0.f);
        o.y = fmaxf(a1 * s + bb.y, 0.f);
        o.z = fmaxf(a2 * s + bb.z, 0.f);
        o.w = fmaxf(a3 * s + bb.w, 0.f);
        __builtin_nontemporal_store(o, reinterpret_cast<f32x4*>(out + (size_t)n * NCH + sl * 4));
    }
}

// ---------------------------------------------------------------------------
extern "C" void kernel_launch(void* const* d_in, const int* in_sizes, int n_in,
                              void* d_out, int out_size, void* d_ws, size_t ws_size,
                              hipStream_t stream) {
    const float* x = (const float*)d_in[0];
    const int* ei = (const int*)d_in[1];  // int32 view; int64 handled in-kernel
    const float* W = (const float*)d_in[2];
    const float* bias = (const float*)d_in[3];
    float* out = (float*)d_out;

    const int N = in_sizes[0] / NCH;       // 50000
    const int E = in_sizes[1] / 2;         // 1600000
    const int nbuck = (N + BK_TGTS - 1) >> BK_SHIFT;   // 391

    char* w = (char*)d_ws;
    const int padN = (N + 127) & ~127;
    const int padN1 = (N + 1 + 127) & ~127;
    int* offsets = (int*)w;                 w += (size_t)padN1 * 4;
    float* dinv = (float*)w;                w += (size_t)padN * 4;
    int* bcur = (int*)w;                    w += NBUCK_MAX * 4;
    short* whl = (short*)w;                 w += 65536;
    // regionA: bkt (391*5120*4 = 8.0 MB) while building; hb (12.8 MB) after
    uint32_t* bkt = (uint32_t*)w;
    uint32_t* hb = (uint32_t*)w;            w += (size_t)N * (NCH / 2) * 4;
    unsigned short* entries = (unsigned short*)w;  w += (size_t)E * 2;
    (void)ws_size;

    prep_w_kernel<<<8, 256, 0, stream>>>(W, whl, bcur);
    partition_kernel<<<(E + PT_EDGES - 1) / PT_EDGES, 256, 0, stream>>>(ei, E, nbuck, bcur, bkt);
    bucket_sort_kernel<<<nbuck, 256, 0, stream>>>(bkt, bcur, N, nbuck, entries, offsets, dinv);
    gemm_xw_mfma_kernel<<<(N + 127) / 128, 256, 0, stream>>>(x, whl, dinv, hb, N);
    spmm_csr_kernel<<<(N + 3) / 4, 256, 0, stream>>>(hb, entries, offsets, dinv, bias, out, N);
}

// Round 18
// 109.384 us; speedup vs baseline: 1.0631x; 1.0631x over previous
//
#include <hip/hip_runtime.h>
#include <stdint.h>

#define NCH 128            // C_IN == C_OUT == 128
#define BK_SHIFT 7         // 128 targets per bucket
#define BK_TGTS 128
#define NBUCK_MAX 512      // 391 used
#define BKT_CAP 5120       // fixed per-bucket capacity (mean 4092, +16 sigma)
#define PT_EDGES 4096      // edges per partition tile (chunk size ~10.5 -> L2 write coalescing)
#define BS_CAP 5120        // bucket_sort LDS capacity

typedef short bf16x8 __attribute__((ext_vector_type(8)));
typedef float f32x4 __attribute__((ext_vector_type(4)));
typedef float f32x2 __attribute__((ext_vector_type(2)));

// ---------------------------------------------------------------------------
// bf16 helpers (manual RNE pack; decode via bit shift)
// ---------------------------------------------------------------------------
__device__ __forceinline__ unsigned short f2bf(float f) {
    union { float f; uint32_t u; } v; v.f = f;
    uint32_t u = v.u;
    uint32_t r = u + 0x7fffu + ((u >> 16) & 1u);
    return (unsigned short)(r >> 16);
}
__device__ __forceinline__ float bf2f(unsigned short h) {
    return __uint_as_float((uint32_t)h << 16);
}
__device__ __forceinline__ float bflo(uint32_t u) { return __uint_as_float(u << 16); }
__device__ __forceinline__ float bfhi(uint32_t u) { return __uint_as_float(u & 0xffff0000u); }
// decode one u32 (2 bf16) into a packed float pair -> enables v_pk_add_f32
__device__ __forceinline__ f32x2 bfpair(uint32_t u) {
    f32x2 r;
    r.x = __uint_as_float(u << 16);
    r.y = __uint_as_float(u & 0xffff0000u);
    return r;
}

// ---------------------------------------------------------------------------
// prep_w: W (f32 128x128) -> fragment-swizzled bf16 hi/lo table (64 KB).
// Block 0 also zeroes the bucket cursors (replaces a memset dispatch).
// ---------------------------------------------------------------------------
__global__ __launch_bounds__(256) void prep_w_kernel(const float* __restrict__ W,
                                                     short* __restrict__ whl,
                                                     int* __restrict__ bcur) {
    if (blockIdx.x == 0) {
        for (int i = threadIdx.x; i < NBUCK_MAX; i += 256) bcur[i] = 0;
    }
    const int idx = blockIdx.x * 256 + threadIdx.x;   // 2048 = 16 ko x 128 n
    if (idx >= 2048) return;
    const int ko = idx >> 7;
    const int n = idx & 127;
    const int kt = ko >> 2, g = ko & 3;
    const int ct = n >> 4, l16 = n & 15;
    const int row = g * 16 + l16;
    bf16x8 vh, vl;
    #pragma unroll
    for (int e = 0; e < 8; ++e) {
        const float w = W[(size_t)(ko * 8 + e) * NCH + n];
        const unsigned short wh = f2bf(w);
        vh[e] = (short)wh;
        vl[e] = (short)f2bf(w - bf2f(wh));
    }
    *reinterpret_cast<bf16x8*>(&whl[(((0 * 4 + kt) * 8 + ct) * 64 + row) * 8]) = vh;
    *reinterpret_cast<bf16x8*>(&whl[(((1 * 4 + kt) * 8 + ct) * 64 + row) * 8]) = vl;
}

// ---------------------------------------------------------------------------
// Stage 1 (fused detect+count+partition): scatter edges into fixed-capacity
// bucket windows. Packed entry = {c:16 | r:16}. bcur holds final counts.
// LDS staging + NORMAL stores (nt-store = 8x write amp, R15; smaller tiles
// = fragmented chunks, R17).
// ---------------------------------------------------------------------------
__global__ __launch_bounds__(256) void partition_kernel(const int* __restrict__ ei, int E,
                                                        int nbuck,
                                                        int* __restrict__ bcur,
                                                        uint32_t* __restrict__ bkt) {
    __shared__ int hist[NBUCK_MAX];
    __shared__ int cbase[NBUCK_MAX];
    __shared__ uint32_t stage[PT_EDGES];
    __shared__ int s_is64;
    const int t = threadIdx.x;
    const int e0 = blockIdx.x * PT_EDGES;
    const int cnt = min(PT_EDGES, E - e0);

    if (t == 0) s_is64 = 0;
    for (int i = t; i < NBUCK_MAX; i += 256) hist[i] = 0;
    __syncthreads();
    // int64 layout iff high words all zero (values < 50000; random int32 cols
    // can't all be 0 for 128 samples)
    if (t < 128 && ei[2 * t + 1] != 0) s_is64 = 1;
    __syncthreads();
    const bool is64 = (s_is64 == 0);

    int rank[PT_EDGES / 256];
    #pragma unroll
    for (int j = 0; j < PT_EDGES / 256; ++j) {
        const int i = t + j * 256;
        if (i < cnt) {
            int r, c;
            if (is64) {
                r = reinterpret_cast<const int2*>(ei)[(size_t)(e0 + i)].x;
                c = reinterpret_cast<const int2*>(ei)[(size_t)E + e0 + i].x;
            } else {
                r = ei[e0 + i];
                c = ei[(size_t)E + e0 + i];
            }
            stage[i] = ((uint32_t)c << 16) | (uint32_t)r;
            rank[j] = atomicAdd(&hist[c >> BK_SHIFT], 1);
        }
    }
    __syncthreads();
    for (int b = t; b < nbuck; b += 256) {
        cbase[b] = hist[b] ? atomicAdd(&bcur[b], hist[b]) : 0;
    }
    __syncthreads();
    #pragma unroll
    for (int j = 0; j < PT_EDGES / 256; ++j) {
        const int i = t + j * 256;
        if (i < cnt) {
            const uint32_t p = stage[i];
            const int b = (int)(p >> (16 + BK_SHIFT));
            const int pos = cbase[b] + rank[j];
            if (pos < BKT_CAP) bkt[(size_t)b * BKT_CAP + pos] = p;
        }
    }
}

// ---------------------------------------------------------------------------
// Stage 2: one block per bucket (self-computes its CSR base from bcur).
// Counting sort in LDS -> CSR offsets, dinv, u16 src entries.
// uint4-vectorized window read; single-wave shfl scan for the 128 histogram.
// ---------------------------------------------------------------------------
__global__ __launch_bounds__(256) void bucket_sort_kernel(const uint32_t* __restrict__ bkt,
                                                          const int* __restrict__ bcur,
                                                          int N, int nbuck,
                                                          unsigned short* __restrict__ entries,
                                                          int* __restrict__ offsets,
                                                          float* __restrict__ dinv) {
    __shared__ uint32_t se[BS_CAP];
    __shared__ int hist[BK_TGTS];
    __shared__ int lofs[BK_TGTS];
    __shared__ int s_beg;
    const int b = blockIdx.x;
    const int t = threadIdx.x;
    const int c0 = b << BK_SHIFT;
    const int ntgt = min(BK_TGTS, N - c0);

    for (int i = t; i < BK_TGTS; i += 256) hist[i] = 0;
    if (t < 64) {
        int sum = 0;
        for (int i = t; i < b; i += 64) sum += min(bcur[i], BKT_CAP);
        #pragma unroll
        for (int d = 1; d < 64; d <<= 1) sum += __shfl_xor(sum, d);
        if (t == 0) s_beg = sum;
    }
    __syncthreads();
    const int beg = s_beg;
    const int nE = min(bcur[b], BKT_CAP);
    const int nE4 = nE & ~3;
    const uint32_t* win = bkt + (size_t)b * BKT_CAP;

    for (int i = t * 4; i < nE4; i += 1024) {
        const uint4 p = *reinterpret_cast<const uint4*>(win + i);
        *reinterpret_cast<uint4*>(&se[i]) = p;
        atomicAdd(&hist[(int)(p.x >> 16) - c0], 1);
        atomicAdd(&hist[(int)(p.y >> 16) - c0], 1);
        atomicAdd(&hist[(int)(p.z >> 16) - c0], 1);
        atomicAdd(&hist[(int)(p.w >> 16) - c0], 1);
    }
    for (int i = nE4 + t; i < nE; i += 256) {
        const uint32_t p = win[i];
        se[i] = p;
        atomicAdd(&hist[(int)(p >> 16) - c0], 1);
    }
    __syncthreads();

    // exclusive scan of hist[0..127] in wave 0: lane owns {2t, 2t+1}
    if (t < 64) {
        const int h0 = hist[2 * t], h1 = hist[2 * t + 1];
        int s = h0 + h1;
        #pragma unroll
        for (int d = 1; d < 64; d <<= 1) {
            const int u = __shfl_up(s, d);
            if (t >= d) s += u;
        }
        const int ex = s - (h0 + h1);
        lofs[2 * t] = ex;
        lofs[2 * t + 1] = ex + h0;
    }
    __syncthreads();

    for (int i = t; i < ntgt; i += 256) {
        offsets[c0 + i] = beg + lofs[i];
        dinv[c0 + i] = rsqrtf((float)(hist[i] + 1));
    }
    if (t == 0 && b == nbuck - 1) offsets[N] = beg + nE;
    __syncthreads();

    // reuse hist as scatter cursors
    for (int i = t; i < BK_TGTS; i += 256) hist[i] = lofs[i];
    __syncthreads();
    for (int i = t * 4; i < nE4; i += 1024) {
        const uint4 p = *reinterpret_cast<const uint4*>(&se[i]);
        int pos;
        pos = atomicAdd(&hist[(int)(p.x >> 16) - c0], 1); entries[beg + pos] = (unsigned short)(p.x & 0xffffu);
        pos = atomicAdd(&hist[(int)(p.y >> 16) - c0], 1); entries[beg + pos] = (unsigned short)(p.y & 0xffffu);
        pos = atomicAdd(&hist[(int)(p.z >> 16) - c0], 1); entries[beg + pos] = (unsigned short)(p.z & 0xffffu);
        pos = atomicAdd(&hist[(int)(p.w >> 16) - c0], 1); entries[beg + pos] = (unsigned short)(p.w & 0xffffu);
    }
    for (int i = nE4 + t; i < nE; i += 256) {
        const uint32_t p = se[i];
        const int pos = atomicAdd(&hist[(int)(p >> 16) - c0], 1);
        entries[beg + pos] = (unsigned short)(p & 0xffffu);
    }
}

// ---------------------------------------------------------------------------
// h = x @ W via MFMA bf16, 3-term split (from precomputed Wh/Wl table);
// output pre-scaled by dinv[row], flat layout hb[row][64 u32].
// 128 rows/block (two 64-row groups share the staged W and each bh/bl read).
// ---------------------------------------------------------------------------
__global__ __launch_bounds__(256) void gemm_xw_mfma_kernel(const float* __restrict__ x,
                                                           const short* __restrict__ whl,
                                                           const float* __restrict__ dinv,
                                                           uint32_t* __restrict__ hb, int N) {
    __shared__ short sW[2][4][8][64][8];
    const int t = threadIdx.x;

    // pure copy stage: 64 KB from the precomputed table
    {
        short* d = &sW[0][0][0][0][0];
        #pragma unroll
        for (int i = t * 8; i < 2 * 4 * 8 * 64 * 8; i += 256 * 8)
            *reinterpret_cast<bf16x8*>(d + i) = *reinterpret_cast<const bf16x8*>(whl + i);
    }
    __syncthreads();

    const int wave = t >> 6;
    const int lane = t & 63;
    const int g = lane >> 4;
    const int l16 = lane & 15;
    const int row0 = blockIdx.x * 128 + wave * 16;   // group 0; group 1 = +64
    if (row0 >= N) return;

    bf16x8 ah[2][4], al[2][4];
    float dn[2][4];
    #pragma unroll
    for (int grp = 0; grp < 2; ++grp) {
        const int rbase = row0 + grp * 64;
        const int arow = min(rbase + l16, N - 1);
        const float* xr = x + (size_t)arow * NCH + g * 8;
        #pragma unroll
        for (int kt = 0; kt < 4; ++kt) {
            const float4 v0 = *reinterpret_cast<const float4*>(xr + kt * 32);
            const float4 v1 = *reinterpret_cast<const float4*>(xr + kt * 32 + 4);
            const float vv[8] = {v0.x, v0.y, v0.z, v0.w, v1.x, v1.y, v1.z, v1.w};
            #pragma unroll
            for (int e = 0; e < 8; ++e) {
                const unsigned short h16 = f2bf(vv[e]);
                ah[grp][kt][e] = (short)h16;
                al[grp][kt][e] = (short)f2bf(vv[e] - bf2f(h16));
            }
        }
        #pragma unroll
        for (int r = 0; r < 4; ++r) dn[grp][r] = dinv[min(rbase + g * 4 + r, N - 1)];
    }

    #pragma unroll
    for (int ct = 0; ct < 8; ++ct) {
        f32x4 accA = {0.f, 0.f, 0.f, 0.f};
        f32x4 accB = {0.f, 0.f, 0.f, 0.f};
        #pragma unroll
        for (int kt = 0; kt < 4; ++kt) {
            const bf16x8 bh = *reinterpret_cast<const bf16x8*>(&sW[0][kt][ct][lane][0]);
            const bf16x8 bl = *reinterpret_cast<const bf16x8*>(&sW[1][kt][ct][lane][0]);
            accA = __builtin_amdgcn_mfma_f32_16x16x32_bf16(ah[0][kt], bh, accA, 0, 0, 0);
            accA = __builtin_amdgcn_mfma_f32_16x16x32_bf16(al[0][kt], bh, accA, 0, 0, 0);
            accA = __builtin_amdgcn_mfma_f32_16x16x32_bf16(ah[0][kt], bl, accA, 0, 0, 0);
            accB = __builtin_amdgcn_mfma_f32_16x16x32_bf16(ah[1][kt], bh, accB, 0, 0, 0);
            accB = __builtin_amdgcn_mfma_f32_16x16x32_bf16(al[1][kt], bh, accB, 0, 0, 0);
            accB = __builtin_amdgcn_mfma_f32_16x16x32_bf16(ah[1][kt], bl, accB, 0, 0, 0);
        }
        // C/D: col = ct*16 + (lane&15), row = rbase + (lane>>4)*4 + r
        #pragma unroll
        for (int grp = 0; grp < 2; ++grp) {
            const f32x4 acc = grp ? accB : accA;
            #pragma unroll
            for (int r = 0; r < 4; ++r) {
                const float v = acc[r] * dn[grp][r];
                const float o = __shfl_xor(v, 1);
                const int wrow = row0 + grp * 64 + g * 4 + r;
                if ((lane & 1) == 0 && wrow < N) {
                    const uint32_t p = (uint32_t)f2bf(v) | ((uint32_t)f2bf(o) << 16);
                    hb[(size_t)wrow * (NCH / 2) + ct * 8 + (l16 >> 1)] = p;
                }
            }
        }
    }
}

// ---------------------------------------------------------------------------
// SpMM: one wave per target node. 32 lanes x 8 B cover the 256 B bf16 row.
// Halves process even/odd local edges; first 64 entries preloaded into regs
// and broadcast via __shfl. 8-deep unroll -> 8 gathers in flight per half.
// Packed-pair (v_pk_add_f32) accumulate; non-temporal out store (full-line
// streaming only -- nt is NOT safe for scatters, see R15).
// ---------------------------------------------------------------------------
__global__ __launch_bounds__(256) void spmm_csr_kernel(const uint32_t* __restrict__ hb,
                                                       const unsigned short* __restrict__ entries,
                                                       const int* __restrict__ offsets,
                                                       const float* __restrict__ dinv,
                                                       const float* __restrict__ bias,
                                                       float* __restrict__ out, int N) {
    const int lane = threadIdx.x & 63;
    const int n = blockIdx.x * 4 + (threadIdx.x >> 6);
    if (n >= N) return;

    const int half = lane >> 5;
    const int sl = lane & 31;          // covers cols sl*4 .. sl*4+3

    const int beg = offsets[n];
    const int end = offsets[n + 1];
    const int len = end - beg;
    const int cnt0 = min(len, 64);

    int pre = 0;
    if (beg + lane < end) pre = (int)__builtin_nontemporal_load(entries + beg + lane);

    const uint32_t* __restrict__ hbs = hb + sl * 2;
    f32x2 acc01 = {0.f, 0.f};
    f32x2 acc23 = {0.f, 0.f};

    int j = 0;
    // 8-deep: all elements valid for BOTH halves iff 2j+16 <= cnt0
    for (; 2 * j + 16 <= cnt0; j += 8) {
        const int i0 = 2 * j + half;
        const int s0 = __shfl(pre, i0);
        const int s1 = __shfl(pre, i0 + 2);
        const int s2 = __shfl(pre, i0 + 4);
        const int s3 = __shfl(pre, i0 + 6);
        const int s4 = __shfl(pre, i0 + 8);
        const int s5 = __shfl(pre, i0 + 10);
        const int s6 = __shfl(pre, i0 + 12);
        const int s7 = __shfl(pre, i0 + 14);
        const uint2 u0 = *reinterpret_cast<const uint2*>(hbs + (size_t)s0 * (NCH / 2));
        const uint2 u1 = *reinterpret_cast<const uint2*>(hbs + (size_t)s1 * (NCH / 2));
        const uint2 u2 = *reinterpret_cast<const uint2*>(hbs + (size_t)s2 * (NCH / 2));
        const uint2 u3 = *reinterpret_cast<const uint2*>(hbs + (size_t)s3 * (NCH / 2));
        const uint2 u4 = *reinterpret_cast<const uint2*>(hbs + (size_t)s4 * (NCH / 2));
        const uint2 u5 = *reinterpret_cast<const uint2*>(hbs + (size_t)s5 * (NCH / 2));
        const uint2 u6 = *reinterpret_cast<const uint2*>(hbs + (size_t)s6 * (NCH / 2));
        const uint2 u7 = *reinterpret_cast<const uint2*>(hbs + (size_t)s7 * (NCH / 2));
        acc01 += bfpair(u0.x); acc23 += bfpair(u0.y);
        acc01 += bfpair(u1.x); acc23 += bfpair(u1.y);
        acc01 += bfpair(u2.x); acc23 += bfpair(u2.y);
        acc01 += bfpair(u3.x); acc23 += bfpair(u3.y);
        acc01 += bfpair(u4.x); acc23 += bfpair(u4.y);
        acc01 += bfpair(u5.x); acc23 += bfpair(u5.y);
        acc01 += bfpair(u6.x); acc23 += bfpair(u6.y);
        acc01 += bfpair(u7.x); acc23 += bfpair(u7.y);
    }
    for (; 2 * j + 8 <= cnt0; j += 4) {
        const int i0 = 2 * j + half;
        const int s0 = __shfl(pre, i0);
        const int s1 = __shfl(pre, i0 + 2);
        const int s2 = __shfl(pre, i0 + 4);
        const int s3 = __shfl(pre, i0 + 6);
        const uint2 u0 = *reinterpret_cast<const uint2*>(hbs + (size_t)s0 * (NCH / 2));
        const uint2 u1 = *reinterpret_cast<const uint2*>(hbs + (size_t)s1 * (NCH / 2));
        const uint2 u2 = *reinterpret_cast<const uint2*>(hbs + (size_t)s2 * (NCH / 2));
        const uint2 u3 = *reinterpret_cast<const uint2*>(hbs + (size_t)s3 * (NCH / 2));
        acc01 += bfpair(u0.x); acc23 += bfpair(u0.y);
        acc01 += bfpair(u1.x); acc23 += bfpair(u1.y);
        acc01 += bfpair(u2.x); acc23 += bfpair(u2.y);
        acc01 += bfpair(u3.x); acc23 += bfpair(u3.y);
    }
    // remainder: uniform count over halves; invalid element zeroed
    for (; 2 * j < cnt0; ++j) {
        const int i0 = 2 * j + half;
        const int s0 = __shfl(pre, min(i0, 63));
        uint2 u0 = *reinterpret_cast<const uint2*>(hbs + (size_t)s0 * (NCH / 2));
        if (i0 >= cnt0) { u0.x = 0u; u0.y = 0u; }
        acc01 += bfpair(u0.x); acc23 += bfpair(u0.y);
    }
    // rare tail (deg > 64): direct loads, no shfl
    for (int jj = beg + 64 + half; jj < end; jj += 2) {
        const int s0 = __builtin_nontemporal_load(entries + jj);
        const uint2 u0 = *reinterpret_cast<const uint2*>(hbs + (size_t)s0 * (NCH / 2));
        acc01 += bfpair(u0.x); acc23 += bfpair(u0.y);
    }

    float a0 = acc01.x, a1 = acc01.y, a2 = acc23.x, a3 = acc23.y;
    a0 += __shfl_xor(a0, 32);
    a1 += __shfl_xor(a1, 32);
    a2 += __shfl_xor(a2, 32);
    a3 += __shfl_xor(a3, 32);

    // self-loop: hb row n is dinv[n]*h[n]
    const uint2 us = *reinterpret_cast<const uint2*>(hbs + (size_t)n * (NCH / 2));
    a0 += bflo(us.x); a1 += bfhi(us.x); a2 += bflo(us.y); a3 += bfhi(us.y);

    const float s = dinv[n];
    if (half == 0) {
        const float4 bb = reinterpret_cast<const float4*>(bias)[sl];
        f32x4 o;
        o.x = fmaxf(a0 * s + bb.x, 0.f);
        o.y = fmaxf(a1 * s + bb.y, 0.f);
        o.z = fmaxf(a2 * s + bb.z, 0.f);
        o.w = fmaxf(a3 * s + bb.w, 0.f);
        __builtin_nontemporal_store(o, reinterpret_cast<f32x4*>(out + (size_t)n * NCH + sl * 4));
    }
}

// ---------------------------------------------------------------------------
extern "C" void kernel_launch(void* const* d_in, const int* in_sizes, int n_in,
                              void* d_out, int out_size, void* d_ws, size_t ws_size,
                              hipStream_t stream) {
    const float* x = (const float*)d_in[0];
    const int* ei = (const int*)d_in[1];  // int32 view; int64 handled in-kernel
    const float* W = (const float*)d_in[2];
    const float* bias = (const float*)d_in[3];
    float* out = (float*)d_out;

    const int N = in_sizes[0] / NCH;       // 50000
    const int E = in_sizes[1] / 2;         // 1600000
    const int nbuck = (N + BK_TGTS - 1) >> BK_SHIFT;   // 391

    char* w = (char*)d_ws;
    const int padN = (N + 127) & ~127;
    const int padN1 = (N + 1 + 127) & ~127;
    int* offsets = (int*)w;                 w += (size_t)padN1 * 4;
    float* dinv = (float*)w;                w += (size_t)padN * 4;
    int* bcur = (int*)w;                    w += NBUCK_MAX * 4;
    short* whl = (short*)w;                 w += 65536;
    // regionA: bkt (391*5120*4 = 8.0 MB) while building; hb (12.8 MB) after
    uint32_t* bkt = (uint32_t*)w;
    uint32_t* hb = (uint32_t*)w;            w += (size_t)N * (NCH / 2) * 4;
    unsigned short* entries = (unsigned short*)w;  w += (size_t)E * 2;
    (void)ws_size;

    prep_w_kernel<<<8, 256, 0, stream>>>(W, whl, bcur);
    partition_kernel<<<(E + PT_EDGES - 1) / PT_EDGES, 256, 0, stream>>>(ei, E, nbuck, bcur, bkt);
    bucket_sort_kernel<<<nbuck, 256, 0, stream>>>(bkt, bcur, N, nbuck, entries, offsets, dinv);
    gemm_xw_mfma_kernel<<<(N + 127) / 128, 256, 0, stream>>>(x, whl, dinv, hb, N);
    spmm_csr_kernel<<<(N + 3) / 4, 256, 0, stream>>>(hb, entries, offsets, dinv, bias, out, N);
}